// Round 3
// baseline (316.847 us; speedup 1.0000x reference)
//
#include <hip/hip_runtime.h>

#define N_ 64
#define C_ 64
#define T_ 256
#define V_ 25
#define R_ 8
#define O_ 64

constexpr int TV = T_ * V_;           // 6400
constexpr float INV_T = 1.0f / (float)T_;
constexpr int TC = 16;                // t's per fused block
constexpr int NPOS = TC * V_;         // 400
constexpr int NT = NPOS / 16;         // 25 N-tiles
constexpr int XBS = NPOS + 2;         // padded pos-slots per cblk
constexpr int UP = 40;                // padded u dim (multiple of 8, >32)

typedef __attribute__((ext_vector_type(8))) short s8v;   // 8 bf16 = 4 VGPR
typedef __attribute__((ext_vector_type(4))) float f4v;   // MFMA acc

__device__ __forceinline__ unsigned short f2bf(float f) {   // RNE f32->bf16
    union { float f; unsigned u; } v; v.f = f;
    unsigned r = v.u + 0x7FFFu + ((v.u >> 16) & 1u);
    return (unsigned short)(r >> 16);
}

// -------- Kernel 1: xm[n][c][v] = mean_t x[n][c][t][v] --------
__global__ __launch_bounds__(256) void k_mean(const float* __restrict__ x,
                                              float* __restrict__ xm) {
    __shared__ float part[8 * V_];
    const int bid = blockIdx.x;           // n*C + c
    const int tid = threadIdx.x;
    const float* xp = x + (size_t)bid * TV;
    if (tid < 200) {
        const int vid = tid % V_;
        const int seg = tid / V_;
        float s = 0.f;
        const float* p = xp + seg * 32 * V_ + vid;
        #pragma unroll
        for (int j = 0; j < 32; ++j) s += p[j * V_];
        part[tid] = s;
    }
    __syncthreads();
    if (tid < V_) {
        float s = 0.f;
        #pragma unroll
        for (int k = 0; k < 8; ++k) s += part[k * V_ + tid];
        xm[(size_t)bid * V_ + tid] = s * INV_T;
    }
}

// -------- Kernel 2: d[n][o][u][v] = sum_r w4[o,r]*tanh(x1[n,r,u]-x2[n,r,v]) + b4[o] + A[u,v]
__global__ __launch_bounds__(256) void k_dmat(const float* __restrict__ xm,
                                              const float* __restrict__ A,
                                              const float* __restrict__ w1,
                                              const float* __restrict__ b1,
                                              const float* __restrict__ w2,
                                              const float* __restrict__ b2,
                                              const float* __restrict__ w4,
                                              const float* __restrict__ b4,
                                              float* __restrict__ d) {
    __shared__ float xms[C_][V_];
    __shared__ float x1s[R_][V_];
    __shared__ float x2s[R_][V_];
    const int n = blockIdx.x;
    const int og = blockIdx.y * 16;
    const int tid = threadIdx.x;

    for (int i = tid; i < C_ * V_; i += 256)
        xms[i / V_][i % V_] = xm[(size_t)n * C_ * V_ + i];
    __syncthreads();

    for (int i = tid; i < 2 * R_ * V_; i += 256) {
        const int j = i % (R_ * V_);
        const int r = j / V_, v = j % V_;
        const bool first = (i < R_ * V_);
        const float* w = first ? w1 : w2;
        float acc = first ? b1[r] : b2[r];
        #pragma unroll
        for (int c = 0; c < C_; ++c) acc += w[r * C_ + c] * xms[c][v];
        if (first) x1s[r][v] = acc;
        else       x2s[r][v] = acc;
    }
    __syncthreads();

    for (int p = tid; p < V_ * V_; p += 256) {
        const int u = p / V_, v = p % V_;
        float adjr[R_];
        #pragma unroll
        for (int r = 0; r < R_; ++r) adjr[r] = tanhf(x1s[r][u] - x2s[r][v]);
        const float a = A[u * V_ + v];
        #pragma unroll
        for (int oo = 0; oo < 16; ++oo) {
            const int o = og + oo;
            float acc = b4[o];
            #pragma unroll
            for (int r = 0; r < R_; ++r) acc = fmaf(w4[o * R_ + r], adjr[r], acc);
            d[(((size_t)n * O_ + o) * V_ + u) * V_ + v] = acc + a;  // ALPHA == 1
        }
    }
}

// -------- Fused kernel: x3 = w3*x + b3 (MFMA GEMM1), out = x3 @ d (MFMA GEMM2)
__global__ __launch_bounds__(256) void k_fused(const float* __restrict__ x,
                                               const float* __restrict__ w3,
                                               const float* __restrict__ b3,
                                               const float* __restrict__ dmat,
                                               float* __restrict__ out) {
    __shared__ __align__(16) unsigned short xb[8][XBS][8];   // [cblk][pos][cin] 51.5KB bf16
    __shared__ __align__(16) unsigned short x3b[32][TC][UP]; // [o-half][t][u]  41.0KB bf16
    __shared__ __align__(16) unsigned short dT[16][32][UP];  // [o-chunk][v][u] 41.0KB bf16
    // total 130.3 KB < 160 KB -> 1 block/CU

    const int n    = blockIdx.y;
    const int tc   = blockIdx.x;
    const int tid  = threadIdx.x;
    const int lane = tid & 63;
    const int wave = tid >> 6;
    const int l16  = lane & 15;
    const int lg   = lane >> 4;     // 0..3

    // zero all of x3b once (u-pad must be 0 for GEMM2's K=32 zero-padding)
    {
        s8v z = (s8v)0;
        #pragma unroll
        for (int i = 0; i < 10; ++i)
            *(s8v*)((unsigned short*)x3b + (size_t)(i * 256 + tid) * 8) = z;
    }

    // hoist w3 A-frags (bf16) and b3 into registers
    // afr[h][m][kh] elem j = w3[o = h*32+m*16+l16][c = kh*32+lg*8+j]
    s8v afr[2][2][2];
    f4v b3r[2][2];
    #pragma unroll
    for (int h = 0; h < 2; ++h) {
        #pragma unroll
        for (int m = 0; m < 2; ++m) {
            #pragma unroll
            for (int kh = 0; kh < 2; ++kh) {
                const float* wp = w3 + (h * 32 + m * 16 + l16) * C_ + kh * 32 + lg * 8;
                s8v f;
                #pragma unroll
                for (int j = 0; j < 8; ++j) f[j] = (short)f2bf(wp[j]);
                afr[h][m][kh] = f;
            }
            b3r[h][m] = *(const f4v*)(b3 + h * 32 + m * 16 + lg * 4);
        }
    }

    // stage x chunk -> xb (bf16), wave handles 2 cblks; b128 LDS writes
    #pragma unroll 1
    for (int cb = wave * 2; cb < wave * 2 + 2; ++cb) {
        #pragma unroll 1
        for (int i = 0; i < 7; ++i) {
            const int pos = i * 64 + lane;
            if (pos < NPOS) {
                s8v pk;
                #pragma unroll
                for (int cin = 0; cin < 8; ++cin) {
                    const int c = cb * 8 + cin;
                    pk[cin] = (short)f2bf(x[((size_t)(n * C_ + c)) * TV + tc * NPOS + pos]);
                }
                *(s8v*)&xb[cb][pos][0] = pk;
            }
        }
    }
    __syncthreads();

    const float* dn = dmat + (size_t)n * O_ * V_ * V_;
    float* on = out + (size_t)n * O_ * TV + (size_t)tc * TC * V_;

    #pragma unroll 1
    for (int h = 0; h < 2; ++h) {
        // ---- GEMM1 for o-half h: x3[o][pos] = sum_c w3[o][c]*x[c][pos] + b3[o]
        #pragma unroll
        for (int i = 0; i < 7; ++i) {
            const int nt = wave + 4 * i;
            if (nt < NT) {
                const int pos = nt * 16 + l16;
                const int t = pos / 25, u = pos - 25 * t;
                const s8v bf0 = *(const s8v*)&xb[lg][pos][0];      // kh=0: cblk=lg
                const s8v bf1 = *(const s8v*)&xb[4 + lg][pos][0];  // kh=1: cblk=4+lg
                #pragma unroll
                for (int m = 0; m < 2; ++m) {
                    f4v a = (f4v)0.f;
                    a = __builtin_amdgcn_mfma_f32_16x16x32_bf16(afr[h][m][0], bf0, a, 0, 0, 0);
                    a = __builtin_amdgcn_mfma_f32_16x16x32_bf16(afr[h][m][1], bf1, a, 0, 0, 0);
                    // C: col=l16=pos-in-tile, row=lg*4+r = o-in-tile (m89-verified)
                    #pragma unroll
                    for (int r = 0; r < 4; ++r) {
                        const int ol = m * 16 + lg * 4 + r;        // o within half
                        x3b[ol][t][u] = f2bf(a[r] + b3r[h][m][r]);
                    }
                }
            }
        }
        __syncthreads();   // x3b(half h) ready

        // ---- GEMM2 in two 16-o chunks: out[t][v] = sum_u x3[t][u]*d[o][u][v]
        #pragma unroll 1
        for (int cg = 0; cg < 2; ++cg) {
            // stage dT chunk: d[n][o][u][v] fp32 -> dT[ol][v][u] bf16 (transposed)
            #pragma unroll 1
            for (int j = 0; j < 40; ++j) {
                const int idx = j * 256 + tid;
                if (idx < 10000) {
                    const int ol = idx / 625;
                    const int rem = idx - 625 * ol;
                    const int u = rem / 25, v = rem - 25 * u;
                    dT[ol][v][u] = f2bf(dn[(h * 32 + cg * 16 + ol) * 625 + rem]);
                }
            }
            __syncthreads();

            #pragma unroll
            for (int oo = 0; oo < 4; ++oo) {
                const int ol = wave * 4 + oo;          // o within chunk
                const int oh = cg * 16 + ol;           // o within half (x3b idx)
                const int og = h * 32 + oh;            // global o
                // A-frag: x3[t=l16][u=lg*8+j]; B-frags: d[u=lg*8+j][v=l16(+16)]
                const s8v av  = *(const s8v*)&x3b[oh][l16][lg * 8];
                const s8v bv0 = *(const s8v*)&dT[ol][l16][lg * 8];
                const s8v bv1 = *(const s8v*)&dT[ol][16 + l16][lg * 8];
                f4v c0 = (f4v)0.f, c1 = (f4v)0.f;
                c0 = __builtin_amdgcn_mfma_f32_16x16x32_bf16(av, bv0, c0, 0, 0, 0);
                c1 = __builtin_amdgcn_mfma_f32_16x16x32_bf16(av, bv1, c1, 0, 0, 0);
                float* ob = on + (size_t)og * TV;
                #pragma unroll
                for (int r = 0; r < 4; ++r) {
                    const int t = lg * 4 + r;
                    ob[t * 25 + l16] = c0[r];
                    if (l16 < 9) ob[t * 25 + 16 + l16] = c1[r];
                }
            }
            __syncthreads();   // protect dT before next stage / x3b before next half
        }
    }
}

extern "C" void kernel_launch(void* const* d_in, const int* in_sizes, int n_in,
                              void* d_out, int out_size, void* d_ws, size_t ws_size,
                              hipStream_t stream) {
    const float* x  = (const float*)d_in[0];
    const float* A  = (const float*)d_in[1];
    const float* w1 = (const float*)d_in[2];
    const float* b1 = (const float*)d_in[3];
    const float* w2 = (const float*)d_in[4];
    const float* b2 = (const float*)d_in[5];
    const float* w3 = (const float*)d_in[6];
    const float* b3 = (const float*)d_in[7];
    const float* w4 = (const float*)d_in[8];
    const float* b4 = (const float*)d_in[9];

    float* out = (float*)d_out;
    float* xm  = (float*)d_ws;                 // N*C*V floats   (0.41 MB)
    float* dm  = xm + (size_t)N_ * C_ * V_;    // N*O*V*V floats (10.24 MB)

    k_mean<<<N_ * C_, 256, 0, stream>>>(x, xm);
    k_dmat<<<dim3(N_, 4), 256, 0, stream>>>(xm, A, w1, b1, w2, b2, w4, b4, dm);
    k_fused<<<dim3(T_ / TC, N_), 256, 0, stream>>>(x, w3, b3, dm, out);
}

// Round 4
// 236.092 us; speedup vs baseline: 1.3420x; 1.3420x over previous
//
#include <hip/hip_runtime.h>

#define N_ 64
#define C_ 64
#define T_ 256
#define V_ 25
#define R_ 8
#define O_ 64
constexpr int TV = T_ * V_;           // 6400
constexpr float INV_T = 1.0f / (float)T_;

// -------- k_A: x3[n][o][tu] = sum_c w3[o,c]*x[n,c,tu] + b3[o]  (into d_out)
//          + xm[n][c][v] partial sums via LDS -> one global atomicAdd pass.
// x read ONCE into xcol registers (launch_bounds caps VGPR at 128 so the
// 64-reg xcol + 16-reg acc stays resident; round-2 ran at 36 VGPR and
// re-loaded x 8x -> VMEM-issue bound).
__global__ __launch_bounds__(256, 4) void k_A(const float* __restrict__ x,
                                              const float* __restrict__ w3,
                                              const float* __restrict__ b3,
                                              float* __restrict__ xm,
                                              float* __restrict__ out) {
    __shared__ float xms[C_ * V_];        // 6.4 KB
    const int n   = blockIdx.y;
    const int tu  = blockIdx.x * 256 + threadIdx.x;
    const int tid = threadIdx.x;

    for (int i = tid; i < C_ * V_; i += 256) xms[i] = 0.f;
    __syncthreads();

    const float* xp = x + (size_t)n * C_ * TV + tu;
    float xcol[C_];
    #pragma unroll
    for (int c = 0; c < C_; ++c) xcol[c] = xp[(size_t)c * TV];   // coalesced, once

    const int v = tu % V_;
    #pragma unroll
    for (int c = 0; c < C_; ++c) atomicAdd(&xms[c * V_ + v], xcol[c]);

    float* op = out + (size_t)n * O_ * TV + tu;
    #pragma unroll 1
    for (int ot = 0; ot < O_ / 16; ++ot) {
        float acc[16];
        #pragma unroll
        for (int oo = 0; oo < 16; ++oo) acc[oo] = b3[ot * 16 + oo];   // uniform
        #pragma unroll
        for (int c = 0; c < C_; ++c) {
            #pragma unroll
            for (int oo = 0; oo < 16; ++oo)
                acc[oo] = fmaf(w3[(ot * 16 + oo) * C_ + c], xcol[c], acc[oo]); // w3 scalar path
        }
        #pragma unroll
        for (int oo = 0; oo < 16; ++oo)
            op[(size_t)(ot * 16 + oo) * TV] = acc[oo];            // coalesced
    }

    __syncthreads();
    for (int i = tid; i < C_ * V_; i += 256)
        atomicAdd(&xm[(size_t)n * C_ * V_ + i], xms[i] * INV_T);
}

// -------- k_dmat: d[n][o][u][v] = sum_r w4[o,r]*tanh(x1[n,r,u]-x2[n,r,v]) + b4[o] + A[u,v]
__global__ __launch_bounds__(256) void k_dmat(const float* __restrict__ xm,
                                              const float* __restrict__ A,
                                              const float* __restrict__ w1,
                                              const float* __restrict__ b1,
                                              const float* __restrict__ w2,
                                              const float* __restrict__ b2,
                                              const float* __restrict__ w4,
                                              const float* __restrict__ b4,
                                              float* __restrict__ d) {
    __shared__ float xms[C_][V_];
    __shared__ float x1s[R_][V_];
    __shared__ float x2s[R_][V_];
    const int n  = blockIdx.x;
    const int og = blockIdx.y * 16;
    const int tid = threadIdx.x;

    for (int i = tid; i < C_ * V_; i += 256)
        xms[i / V_][i % V_] = xm[(size_t)n * C_ * V_ + i];
    __syncthreads();

    for (int i = tid; i < 2 * R_ * V_; i += 256) {
        const int j = i % (R_ * V_);
        const int r = j / V_, v = j % V_;
        const bool first = (i < R_ * V_);
        const float* w = first ? w1 : w2;
        float acc = first ? b1[r] : b2[r];
        #pragma unroll
        for (int c = 0; c < C_; ++c) acc += w[r * C_ + c] * xms[c][v];
        if (first) x1s[r][v] = acc;
        else       x2s[r][v] = acc;
    }
    __syncthreads();

    for (int p = tid; p < V_ * V_; p += 256) {
        const int u = p / V_, v = p % V_;
        float adjr[R_];
        #pragma unroll
        for (int r = 0; r < R_; ++r) adjr[r] = tanhf(x1s[r][u] - x2s[r][v]);
        const float a = A[u * V_ + v];
        #pragma unroll
        for (int oo = 0; oo < 16; ++oo) {
            const int o = og + oo;
            float acc = b4[o];
            #pragma unroll
            for (int r = 0; r < R_; ++r) acc = fmaf(w4[o * R_ + r], adjr[r], acc);
            d[(((size_t)n * O_ + o) * V_ + u) * V_ + v] = acc + a;  // ALPHA == 1
        }
    }
}

// -------- k_out (in-place over d_out): out[t][v] = sum_u x3[t][u]*d[u][v] per (n,o)
__global__ __launch_bounds__(256) void k_out(const float* __restrict__ dmat,
                                             float* __restrict__ io) {
    __shared__ float xt[TV];              // 25.6 KB
    const int bid = blockIdx.x;           // n*O + o
    const int tid = threadIdx.x;
    float* base = io + (size_t)bid * TV;
    #pragma unroll
    for (int k = 0; k < TV / 256; ++k)
        xt[k * 256 + tid] = base[k * 256 + tid];   // coalesced stage
    __syncthreads();
    float row[V_];
    #pragma unroll
    for (int u = 0; u < V_; ++u) row[u] = xt[tid * V_ + u];  // odd stride: ~2-way, free
    const float* dm = dmat + (size_t)bid * V_ * V_;
    float acc[V_];
    #pragma unroll
    for (int v = 0; v < V_; ++v) acc[v] = 0.f;
    #pragma unroll
    for (int u = 0; u < V_; ++u) {
        #pragma unroll
        for (int v = 0; v < V_; ++v)
            acc[v] = fmaf(row[u], dm[u * V_ + v], acc[v]);   // dm uniform -> scalar loads
    }
    __syncthreads();
    #pragma unroll
    for (int v = 0; v < V_; ++v) xt[tid * V_ + v] = acc[v];
    __syncthreads();
    #pragma unroll
    for (int k = 0; k < TV / 256; ++k)
        base[k * 256 + tid] = xt[k * 256 + tid];   // coalesced store
}

extern "C" void kernel_launch(void* const* d_in, const int* in_sizes, int n_in,
                              void* d_out, int out_size, void* d_ws, size_t ws_size,
                              hipStream_t stream) {
    const float* x  = (const float*)d_in[0];
    const float* A  = (const float*)d_in[1];
    const float* w1 = (const float*)d_in[2];
    const float* b1 = (const float*)d_in[3];
    const float* w2 = (const float*)d_in[4];
    const float* b2 = (const float*)d_in[5];
    const float* w3 = (const float*)d_in[6];
    const float* b3 = (const float*)d_in[7];
    const float* w4 = (const float*)d_in[8];
    const float* b4 = (const float*)d_in[9];

    float* out = (float*)d_out;
    float* xm  = (float*)d_ws;                 // N*C*V floats   (0.41 MB)
    float* dm  = xm + (size_t)N_ * C_ * V_;    // N*O*V*V floats (10.24 MB)

    hipMemsetAsync(xm, 0, (size_t)N_ * C_ * V_ * sizeof(float), stream);
    k_A<<<dim3(TV / 256, N_), 256, 0, stream>>>(x, w3, b3, xm, out);
    k_dmat<<<dim3(N_, 4), 256, 0, stream>>>(xm, A, w1, b1, w2, b2, w4, b4, dm);
    k_out<<<N_ * O_, 256, 0, stream>>>(dm, out);
}

// Round 5
// 137.795 us; speedup vs baseline: 2.2994x; 1.7134x over previous
//
#include <hip/hip_runtime.h>

#define N_ 64
#define C_ 64
#define T_ 256
#define V_ 25
#define R_ 8
#define O_ 64
constexpr int TV = T_ * V_;           // 6400
constexpr float INV_T = 1.0f / (float)T_;

typedef __attribute__((ext_vector_type(8))) short s8v;   // 8 bf16 = 4 VGPR
typedef __attribute__((ext_vector_type(4))) float f4v;   // MFMA acc

__device__ __forceinline__ unsigned short f2bf(float f) {   // RNE f32->bf16
    union { float f; unsigned u; } v; v.f = f;
    unsigned r = v.u + 0x7FFFu + ((v.u >> 16) & 1u);
    return (unsigned short)(r >> 16);
}

// -------- k_mean: xm[n][c][v] = mean_t x[n][c][t][v]  (round-2 proven, ~19us)
__global__ __launch_bounds__(256) void k_mean(const float* __restrict__ x,
                                              float* __restrict__ xm) {
    __shared__ float part[8 * V_];
    const int bid = blockIdx.x;           // n*C + c
    const int tid = threadIdx.x;
    const float* xp = x + (size_t)bid * TV;
    if (tid < 200) {
        const int vid = tid % V_;
        const int seg = tid / V_;
        float s = 0.f;
        const float* p = xp + seg * 32 * V_ + vid;
        #pragma unroll
        for (int j = 0; j < 32; ++j) s += p[j * V_];
        part[tid] = s;
    }
    __syncthreads();
    if (tid < V_) {
        float s = 0.f;
        #pragma unroll
        for (int k = 0; k < 8; ++k) s += part[k * V_ + tid];
        xm[(size_t)bid * V_ + tid] = s * INV_T;
    }
}

// -------- k_dmat: d[n][o][u][v] = sum_r w4[o,r]*tanh(x1[n,r,u]-x2[n,r,v]) + b4[o] + A[u,v]
__global__ __launch_bounds__(256) void k_dmat(const float* __restrict__ xm,
                                              const float* __restrict__ A,
                                              const float* __restrict__ w1,
                                              const float* __restrict__ b1,
                                              const float* __restrict__ w2,
                                              const float* __restrict__ b2,
                                              const float* __restrict__ w4,
                                              const float* __restrict__ b4,
                                              float* __restrict__ d) {
    __shared__ float xms[C_][V_];
    __shared__ float x1s[R_][V_];
    __shared__ float x2s[R_][V_];
    const int n  = blockIdx.x;
    const int og = blockIdx.y * 16;
    const int tid = threadIdx.x;

    for (int i = tid; i < C_ * V_; i += 256)
        xms[i / V_][i % V_] = xm[(size_t)n * C_ * V_ + i];
    __syncthreads();

    for (int i = tid; i < 2 * R_ * V_; i += 256) {
        const int j = i % (R_ * V_);
        const int r = j / V_, v = j % V_;
        const bool first = (i < R_ * V_);
        const float* w = first ? w1 : w2;
        float acc = first ? b1[r] : b2[r];
        #pragma unroll
        for (int c = 0; c < C_; ++c) acc += w[r * C_ + c] * xms[c][v];
        if (first) x1s[r][v] = acc;
        else       x2s[r][v] = acc;
    }
    __syncthreads();

    for (int p = tid; p < V_ * V_; p += 256) {
        const int u = p / V_, v = p % V_;
        float adjr[R_];
        #pragma unroll
        for (int r = 0; r < R_; ++r) adjr[r] = tanhf(x1s[r][u] - x2s[r][v]);
        const float a = A[u * V_ + v];
        #pragma unroll
        for (int oo = 0; oo < 16; ++oo) {
            const int o = og + oo;
            float acc = b4[o];
            #pragma unroll
            for (int r = 0; r < R_; ++r) acc = fmaf(w4[o * R_ + r], adjr[r], acc);
            d[(((size_t)n * O_ + o) * V_ + u) * V_ + v] = acc + a;  // ALPHA == 1
        }
    }
}

// -------- k_x3m: x3[n][o][tu] = sum_c w3[o,c]*x[n,c,tu] + b3[o]  via MFMA, zero LDS.
// wave <-> one 16-pos N-tile; A-frags (w3) hoisted; B-frags direct from global;
// C-frags stored direct. Layout conventions identical to the round-3 kernel
// that passed correctness: A lane: row=o=l16, k=c=lg*8+j; B lane: col=pos=l16,
// k=c=lg*8+j; C lane: col=pos=l16, row=o=lg*4+r.
__global__ __launch_bounds__(256) void k_x3m(const float* __restrict__ x,
                                             const float* __restrict__ w3,
                                             const float* __restrict__ b3,
                                             float* __restrict__ x3) {
    const int n    = blockIdx.y;
    const int tid  = threadIdx.x;
    const int lane = tid & 63;
    const int wave = tid >> 6;
    const int l16  = lane & 15;
    const int lg   = lane >> 4;

    // A-frags: afr[m][kh] elem j = w3[m*16+l16][kh*32+lg*8+j]
    s8v afr[4][2];
    #pragma unroll
    for (int m = 0; m < 4; ++m) {
        #pragma unroll
        for (int kh = 0; kh < 2; ++kh) {
            const float* wp = w3 + (m * 16 + l16) * C_ + kh * 32 + lg * 8;
            s8v f;
            #pragma unroll
            for (int j = 0; j < 8; ++j) f[j] = (short)f2bf(wp[j]);
            afr[m][kh] = f;
        }
    }
    f4v b3r[4];
    #pragma unroll
    for (int m = 0; m < 4; ++m)
        b3r[m] = *(const f4v*)(b3 + m * 16 + lg * 4);   // b3[o] for r=0..3

    const int pos = (blockIdx.x * 4 + wave) * 16 + l16;
    const float* xp = x + (size_t)n * C_ * TV + pos;

    // B-frags from global: 16 independent dword loads (64B segments per lg)
    s8v bfr[2];
    #pragma unroll
    for (int kh = 0; kh < 2; ++kh) {
        s8v f;
        #pragma unroll
        for (int j = 0; j < 8; ++j)
            f[j] = (short)f2bf(xp[(size_t)(kh * 32 + lg * 8 + j) * TV]);
        bfr[kh] = f;
    }

    float* op = x3 + (size_t)n * O_ * TV + pos;
    #pragma unroll
    for (int m = 0; m < 4; ++m) {
        f4v acc = (f4v)0.f;
        acc = __builtin_amdgcn_mfma_f32_16x16x32_bf16(afr[m][0], bfr[0], acc, 0, 0, 0);
        acc = __builtin_amdgcn_mfma_f32_16x16x32_bf16(afr[m][1], bfr[1], acc, 0, 0, 0);
        #pragma unroll
        for (int r = 0; r < 4; ++r)
            op[(size_t)(m * 16 + lg * 4 + r) * TV] = acc[r] + b3r[m][r];
    }
}

// -------- k_out (in-place over d_out): out[t][v] = sum_u x3[t][u]*d[u][v] per (n,o)
__global__ __launch_bounds__(256) void k_out(const float* __restrict__ dmat,
                                             float* __restrict__ io) {
    __shared__ float xt[TV];              // 25.6 KB
    const int bid = blockIdx.x;           // n*O + o
    const int tid = threadIdx.x;
    float* base = io + (size_t)bid * TV;
    #pragma unroll
    for (int k = 0; k < TV / 256; ++k)
        xt[k * 256 + tid] = base[k * 256 + tid];   // coalesced stage
    __syncthreads();
    float row[V_];
    #pragma unroll
    for (int u = 0; u < V_; ++u) row[u] = xt[tid * V_ + u];  // odd stride: free
    const float* dm = dmat + (size_t)bid * V_ * V_;
    float acc[V_];
    #pragma unroll
    for (int v = 0; v < V_; ++v) acc[v] = 0.f;
    #pragma unroll
    for (int u = 0; u < V_; ++u) {
        #pragma unroll
        for (int v = 0; v < V_; ++v)
            acc[v] = fmaf(row[u], dm[u * V_ + v], acc[v]);   // dm uniform -> scalar loads
    }
    __syncthreads();
    #pragma unroll
    for (int v = 0; v < V_; ++v) xt[tid * V_ + v] = acc[v];
    __syncthreads();
    #pragma unroll
    for (int k = 0; k < TV / 256; ++k)
        base[k * 256 + tid] = xt[k * 256 + tid];   // coalesced store
}

extern "C" void kernel_launch(void* const* d_in, const int* in_sizes, int n_in,
                              void* d_out, int out_size, void* d_ws, size_t ws_size,
                              hipStream_t stream) {
    const float* x  = (const float*)d_in[0];
    const float* A  = (const float*)d_in[1];
    const float* w1 = (const float*)d_in[2];
    const float* b1 = (const float*)d_in[3];
    const float* w2 = (const float*)d_in[4];
    const float* b2 = (const float*)d_in[5];
    const float* w3 = (const float*)d_in[6];
    const float* b3 = (const float*)d_in[7];
    const float* w4 = (const float*)d_in[8];
    const float* b4 = (const float*)d_in[9];

    float* out = (float*)d_out;
    float* xm  = (float*)d_ws;                 // N*C*V floats   (0.41 MB)
    float* dm  = xm + (size_t)N_ * C_ * V_;    // N*O*V*V floats (10.24 MB)

    k_mean<<<N_ * C_, 256, 0, stream>>>(x, xm);
    k_dmat<<<dim3(N_, 4), 256, 0, stream>>>(xm, A, w1, b1, w2, b2, w4, b4, dm);
    k_x3m<<<dim3(TV / 64, N_), 256, 0, stream>>>(x, w3, b3, out);
    k_out<<<N_ * O_, 256, 0, stream>>>(dm, out);
}

// Round 6
// 83.858 us; speedup vs baseline: 3.7784x; 1.6432x over previous
//
#include <hip/hip_runtime.h>

#define N_ 64
#define C_ 64
#define T_ 256
#define V_ 25
#define R_ 8
#define O_ 64
constexpr int TV = T_ * V_;           // 6400
constexpr float INV_T = 1.0f / (float)T_;
constexpr int TC = 16;                // t's per fused block
constexpr int UP = 40;                // padded u extent (80B rows, 16B-aligned b128)

typedef __attribute__((ext_vector_type(8))) short s8v;   // 8 bf16 = 4 VGPR
typedef __attribute__((ext_vector_type(4))) float f4v;   // MFMA acc

__device__ __forceinline__ unsigned short f2bf(float f) {   // RNE f32->bf16
    union { float f; unsigned u; } v; v.f = f;
    unsigned r = v.u + 0x7FFFu + ((v.u >> 16) & 1u);
    return (unsigned short)(r >> 16);
}

// -------- k_mean: xm[n][c][v] = mean_t x[n][c][t][v]  (proven ~19us, 87% HBM)
__global__ __launch_bounds__(256) void k_mean(const float* __restrict__ x,
                                              float* __restrict__ xm) {
    __shared__ float part[8 * V_];
    const int bid = blockIdx.x;           // n*C + c
    const int tid = threadIdx.x;
    const float* xp = x + (size_t)bid * TV;
    if (tid < 200) {
        const int vid = tid % V_;
        const int seg = tid / V_;
        float s = 0.f;
        const float* p = xp + seg * 32 * V_ + vid;
        #pragma unroll
        for (int j = 0; j < 32; ++j) s += p[j * V_];
        part[tid] = s;
    }
    __syncthreads();
    if (tid < V_) {
        float s = 0.f;
        #pragma unroll
        for (int k = 0; k < 8; ++k) s += part[k * V_ + tid];
        xm[(size_t)bid * V_ + tid] = s * INV_T;
    }
}

// -------- k_dmat: d[n][o][u][v] = sum_r w4[o,r]*tanh(x1[n,r,u]-x2[n,r,v]) + b4[o] + A[u,v]
// now emits bf16 (halves k_F's d traffic; kills its cvt VALU work)
__global__ __launch_bounds__(256) void k_dmat(const float* __restrict__ xm,
                                              const float* __restrict__ A,
                                              const float* __restrict__ w1,
                                              const float* __restrict__ b1,
                                              const float* __restrict__ w2,
                                              const float* __restrict__ b2,
                                              const float* __restrict__ w4,
                                              const float* __restrict__ b4,
                                              unsigned short* __restrict__ d) {
    __shared__ float xms[C_][V_];
    __shared__ float x1s[R_][V_];
    __shared__ float x2s[R_][V_];
    const int n  = blockIdx.x;
    const int og = blockIdx.y * 16;
    const int tid = threadIdx.x;

    for (int i = tid; i < C_ * V_; i += 256)
        xms[i / V_][i % V_] = xm[(size_t)n * C_ * V_ + i];
    __syncthreads();

    for (int i = tid; i < 2 * R_ * V_; i += 256) {
        const int j = i % (R_ * V_);
        const int r = j / V_, v = j % V_;
        const bool first = (i < R_ * V_);
        const float* w = first ? w1 : w2;
        float acc = first ? b1[r] : b2[r];
        #pragma unroll
        for (int c = 0; c < C_; ++c) acc += w[r * C_ + c] * xms[c][v];
        if (first) x1s[r][v] = acc;
        else       x2s[r][v] = acc;
    }
    __syncthreads();

    for (int p = tid; p < V_ * V_; p += 256) {
        const int u = p / V_, v = p % V_;
        float adjr[R_];
        #pragma unroll
        for (int r = 0; r < R_; ++r) adjr[r] = tanhf(x1s[r][u] - x2s[r][v]);
        const float a = A[u * V_ + v];
        #pragma unroll
        for (int oo = 0; oo < 16; ++oo) {
            const int o = og + oo;
            float acc = b4[o];
            #pragma unroll
            for (int r = 0; r < R_; ++r) acc = fmaf(w4[o * R_ + r], adjr[r], acc);
            d[(((size_t)n * O_ + o) * V_ + u) * V_ + v] = f2bf(acc + a);  // ALPHA == 1
        }
    }
}

// -------- k_F: fused GEMM1 (x3 = w3*x + b3, MFMA, global->reg B-frags) ->
//          LDS x3b -> GEMM2 (out = x3 @ d, MFMA, d direct from global bf16).
// 512 thr (8 waves), 80KB LDS -> 2 blocks/CU, 16 waves/CU; ONE barrier.
__global__ __launch_bounds__(512, 4) void k_F(const float* __restrict__ x,
                                              const float* __restrict__ w3,
                                              const float* __restrict__ b3,
                                              const unsigned short* __restrict__ dmat,
                                              float* __restrict__ out) {
    __shared__ __align__(16) unsigned short x3b[O_][TC][UP];   // 80 KB bf16

    const int n    = blockIdx.y;
    const int tc   = blockIdx.x;
    const int tid  = threadIdx.x;
    const int lane = tid & 63;
    const int wave = tid >> 6;      // 0..7
    const int l16  = lane & 15;
    const int lg   = lane >> 4;     // 0..3

    // zero the u-pad [25,32) that GEMM2's K=32 will read (disjoint from GEMM1
    // writes at u<25 -> no extra barrier needed)
    #pragma unroll
    for (int p = 0; p < 2; ++p) {
        const int pair = tid + 512 * p;        // 0..1023 = (o,t)
        const int o = pair >> 4, t = pair & 15;
        #pragma unroll
        for (int u = 25; u < 32; ++u) x3b[o][t][u] = 0;
    }

    // hoist all w3 A-frags: afr[m][kh] elem j = w3[m*16+l16][kh*32+lg*8+j]
    s8v afr[4][2];
    #pragma unroll
    for (int m = 0; m < 4; ++m) {
        #pragma unroll
        for (int kh = 0; kh < 2; ++kh) {
            const float* wp = w3 + (m * 16 + l16) * C_ + kh * 32 + lg * 8;
            s8v f;
            #pragma unroll
            for (int j = 0; j < 8; ++j) f[j] = (short)f2bf(wp[j]);
            afr[m][kh] = f;
        }
    }
    f4v b3r[4];
    #pragma unroll
    for (int m = 0; m < 4; ++m)
        b3r[m] = *(const f4v*)(b3 + m * 16 + lg * 4);

    // ---- GEMM1: 25 pos-tiles of 16, wave-strided (k_x3m pattern, proven)
    const float* xbase = x + (size_t)n * C_ * TV + tc * (TC * V_);
    #pragma unroll 1
    for (int i = 0; i < 4; ++i) {
        const int nt = wave + 8 * i;           // wave-uniform branch
        if (nt < 25) {
            const int pos = nt * 16 + l16;     // < 400
            const int t = pos / 25, u = pos - 25 * t;
            s8v bfr[2];
            #pragma unroll
            for (int kh = 0; kh < 2; ++kh) {
                s8v f;
                #pragma unroll
                for (int j = 0; j < 8; ++j)
                    f[j] = (short)f2bf(xbase[(size_t)(kh * 32 + lg * 8 + j) * TV + pos]);
                bfr[kh] = f;
            }
            #pragma unroll
            for (int m = 0; m < 4; ++m) {
                f4v acc = (f4v)0.f;
                acc = __builtin_amdgcn_mfma_f32_16x16x32_bf16(afr[m][0], bfr[0], acc, 0, 0, 0);
                acc = __builtin_amdgcn_mfma_f32_16x16x32_bf16(afr[m][1], bfr[1], acc, 0, 0, 0);
                // C: col=l16=pos, row=lg*4+r=o-in-tile (verified layout)
                #pragma unroll
                for (int r = 0; r < 4; ++r)
                    x3b[m * 16 + lg * 4 + r][t][u] = f2bf(acc[r] + b3r[m][r]);
            }
        }
    }
    __syncthreads();

    // ---- GEMM2: wave w owns o = w*8..w*8+7. A = x3b[o] (K=32 zero-padded),
    //      B = d[o][u][v] direct from global bf16 (L2/L3-resident).
    const unsigned short* dn = dmat + (size_t)n * O_ * V_ * V_;
    float* on = out + (size_t)n * O_ * TV + tc * (TC * V_);
    #pragma unroll 1
    for (int oo = 0; oo < 8; ++oo) {
        const int o = wave * 8 + oo;
        const s8v av = *(const s8v*)&x3b[o][l16][lg * 8];   // A: row=t=l16, k=u
        const unsigned short* dp = dn + o * (V_ * V_);
        s8v bv0, bv1;
        #pragma unroll
        for (int j = 0; j < 8; ++j) {
            const int u = lg * 8 + j;
            bv0[j] = (u < 25) ? (short)dp[u * 25 + l16] : (short)0;           // B: col=v=l16
            bv1[j] = (u < 25 && l16 < 9) ? (short)dp[u * 25 + 16 + l16] : (short)0;
        }
        f4v c0 = (f4v)0.f, c1 = (f4v)0.f;
        c0 = __builtin_amdgcn_mfma_f32_16x16x32_bf16(av, bv0, c0, 0, 0, 0);
        c1 = __builtin_amdgcn_mfma_f32_16x16x32_bf16(av, bv1, c1, 0, 0, 0);
        float* ob = on + (size_t)o * TV;
        #pragma unroll
        for (int r = 0; r < 4; ++r) {
            const int t = lg * 4 + r;                       // C: row=t, col=v
            ob[t * 25 + l16] = c0[r];
            if (l16 < 9) ob[t * 25 + 16 + l16] = c1[r];
        }
    }
}

extern "C" void kernel_launch(void* const* d_in, const int* in_sizes, int n_in,
                              void* d_out, int out_size, void* d_ws, size_t ws_size,
                              hipStream_t stream) {
    const float* x  = (const float*)d_in[0];
    const float* A  = (const float*)d_in[1];
    const float* w1 = (const float*)d_in[2];
    const float* b1 = (const float*)d_in[3];
    const float* w2 = (const float*)d_in[4];
    const float* b2 = (const float*)d_in[5];
    const float* w3 = (const float*)d_in[6];
    const float* b3 = (const float*)d_in[7];
    const float* w4 = (const float*)d_in[8];
    const float* b4 = (const float*)d_in[9];

    float* out = (float*)d_out;
    float* xm  = (float*)d_ws;                          // N*C*V f32   (0.41 MB)
    unsigned short* dm = (unsigned short*)(xm + (size_t)N_ * C_ * V_);  // N*O*625 bf16 (5.1 MB)

    k_mean<<<N_ * C_, 256, 0, stream>>>(x, xm);
    k_dmat<<<dim3(N_, 4), 256, 0, stream>>>(xm, A, w1, b1, w2, b2, w4, b4, dm);
    k_F<<<dim3(T_ / TC, N_), 512, 0, stream>>>(x, w3, b3, dm, out);
}